// Round 5
// baseline (256245.752 us; speedup 1.0000x reference)
//
#include <hip/hip_runtime.h>
#include <math.h>

#define Bsz 64
#define Tt  1024
#define Dd  256
#define Hh  256
#define TH  512      // entities/slices < T/2, lens >= T/2 -> enc only needed for t < 512
#define G3  768

__device__ __forceinline__ float sigm(float x) { return 1.0f / (1.0f + expf(-x)); }

struct W4 { float4 a, b, c, d; };
struct W6 { float4 a, b, c, d, e, f; };

__device__ __forceinline__ void ld4(W4& w, const float4* __restrict__ p) {
    w.a = p[0]; w.b = p[64]; w.c = p[128]; w.d = p[192];
}
__device__ __forceinline__ void ld6(W6& w, const float4* __restrict__ p) {
    w.a = p[0]; w.b = p[64]; w.c = p[128]; w.d = p[192]; w.e = p[256]; w.f = p[320];
}
// one packed weight f4 (4 k's, 1 col) x 2 batches
__device__ __forceinline__ void fmaW(const float4 w, const float4 v01, const float4 v23,
                                     float& s0, float& s1) {
    s0 = fmaf(w.x, v01.x, fmaf(w.y, v01.z, fmaf(w.z, v23.x, fmaf(w.w, v23.z, s0))));
    s1 = fmaf(w.x, v01.y, fmaf(w.y, v01.w, fmaf(w.z, v23.y, fmaf(w.w, v23.w, s1))));
}

// 8-block double-buffered mog matvec slice; tail prefetches next phase's block0.
template<bool PFG>
__device__ __forceinline__ void mog_phase(
    const float4* __restrict__ Mp, const float4* __restrict__ Lv, int k4b,
    W4& pf, const float4* __restrict__ MpN,
    W6& pfg, const float4* __restrict__ MpG,
    float* __restrict__ s)
{
    W4 wA = pf, wB;
    #pragma unroll
    for (int i = 0; i < 8; ++i) {
        if (i < 7) {
            if ((i & 1) == 0) ld4(wB, Mp + (i + 1) * 256);
            else              ld4(wA, Mp + (i + 1) * 256);
        } else {
            if (PFG) ld6(pfg, MpG);
            else     ld4(pf, MpN);
        }
        const float4 v01 = Lv[2 * (k4b + i)], v23 = Lv[2 * (k4b + i) + 1];
        const W4& w = (i & 1) ? wB : wA;
        fmaW(w.a, v01, v23, s[0], s[1]);
        fmaW(w.b, v01, v23, s[2], s[3]);
        fmaW(w.c, v01, v23, s[4], s[5]);
        fmaW(w.d, v01, v23, s[6], s[7]);
    }
}

// 16-block double-buffered GRU pass (6 cols); tail prefetches pass2 block0 or next-step Q block0.
template<bool LAST>
__device__ __forceinline__ void gru_pass(
    const float4* __restrict__ Wp, const float4* __restrict__ Lv, int k4b,
    W6& pf, const float4* __restrict__ WpN,
    W4& pfm, const float4* __restrict__ MpQ,
    float* __restrict__ s)
{
    W6 wA = pf, wB;
    #pragma unroll
    for (int i = 0; i < 16; ++i) {
        if (i < 15) {
            if ((i & 1) == 0) ld6(wB, Wp + (i + 1) * 768);
            else              ld6(wA, Wp + (i + 1) * 768);
        } else {
            if (LAST) ld4(pfm, MpQ);
            else      ld6(pf, WpN);
        }
        const float4 v01 = Lv[2 * (k4b + i)], v23 = Lv[2 * (k4b + i) + 1];
        const W6& w = (i & 1) ? wB : wA;
        fmaW(w.a, v01, v23, s[0], s[1]);
        fmaW(w.b, v01, v23, s[2], s[3]);
        fmaW(w.c, v01, v23, s[4], s[5]);
        fmaW(w.d, v01, v23, s[6], s[7]);
        fmaW(w.e, v01, v23, s[8], s[9]);
        fmaW(w.f, v01, v23, s[10], s[11]);
    }
}

// Pack weights into [k4][col] float4 blocks: element (k4, col) = W[4k4+0..3][col].
__global__ void pack_k(const float* __restrict__ Q, const float* __restrict__ R,
                       const float* __restrict__ Wih_f, const float* __restrict__ Whh_f,
                       const float* __restrict__ Wih_b, const float* __restrict__ Whh_b,
                       float4* __restrict__ Qp, float4* __restrict__ Rp,
                       float4* __restrict__ Wip, float4* __restrict__ Whp)
{
    int idx = blockIdx.x * 256 + threadIdx.x;
    if (idx < 32768) {                       // 2 dirs * 64 k4 * 256 cols
        int d = idx >> 14, r = idx & 16383;
        int k4 = r >> 8, j = r & 255;
        const float* S = Q + d * 65536;
        Qp[idx] = make_float4(S[(4*k4+0)*256 + j], S[(4*k4+1)*256 + j],
                              S[(4*k4+2)*256 + j], S[(4*k4+3)*256 + j]);
        S = R + d * 65536;
        Rp[idx] = make_float4(S[(4*k4+0)*256 + j], S[(4*k4+1)*256 + j],
                              S[(4*k4+2)*256 + j], S[(4*k4+3)*256 + j]);
    }
    if (idx < 98304) {                       // 2 dirs * 64 k4 * 768 cols
        int d = idx / 49152, r = idx % 49152;
        int k4 = r / 768, col = r % 768;
        const float* Wi = d ? Wih_b : Wih_f;
        const float* Wh = d ? Whh_b : Whh_f;
        Wip[idx] = *(const float4*)(Wi + col * 256 + 4 * k4);
        Whp[idx] = *(const float4*)(Wh + col * 256 + 4 * k4);
    }
}

// One WG of 512 threads per (direction, batch-pair), dir grouped per XCD.
__global__ __launch_bounds__(512) void scan_k(
    const int* __restrict__ sents, const int* __restrict__ lens,
    const float* __restrict__ emb,
    const float* __restrict__ bih_f, const float* __restrict__ bhh_f,
    const float* __restrict__ bih_b, const float* __restrict__ bhh_b,
    const float4* __restrict__ Qp4, const float4* __restrict__ Rp4,
    const float4* __restrict__ Wip4, const float4* __restrict__ Whp4,
    float* __restrict__ enc)
{
    const int w = blockIdx.x;                  // 0..63
    const int dir  = ((w & 7) >= 4) ? 1 : 0;   // dir constant per XCD residue class
    const int pair = (w >> 3) * 4 + (w & 3);   // 0..31, unique per dir
    const int b0 = pair * 2, b1 = b0 + 1;
    const int tid = threadIdx.x;
    const int j   = tid & 255;                 // finalize column (tid<256)
    const int ks8 = tid >> 6;                  // 0..7  k-slice for mogrify (= wave)
    const int l64 = tid & 63;
    const int ks4 = tid >> 7;                  // 0..3  k-slice for GRU
    const int mh  = (tid >> 6) & 1;            // 0: Wih(x), 1: Whh(hm) — wave-uniform
    const int l2  = tid & 63;

    const int k4m = ks8 * 8;                   // mog k4 base
    const int k4e = ks4 * 16;                  // gru k4 base
    const float4* MpQ = Qp4 + dir * 16384 + k4m * 256 + l64;
    const float4* MpR = Rp4 + dir * 16384 + k4m * 256 + l64;
    const float4* Wg  = (mh ? Whp4 : Wip4) + dir * 49152 + (size_t)k4e * 768 + l2;
    const float* bih = dir ? bih_b : bih_f;
    const float* bhh = dir ? bhh_b : bhh_f;

    __shared__ __align__(16) float2 xs[256], hcs[256], hms[256];    // 6 KB
    __shared__ __align__(16) float2 redbuf[4 * 768 * 2];            // 48 KB, overlaid
    float2 (*part)[256] = (float2(*)[256])redbuf;                   // [8][256] (A-D)
    float2 (*giP)[768]  = (float2(*)[768])redbuf;                   // [4][768] (E)
    float2 (*ghP)[768]  = (float2(*)[768])(redbuf + 4 * 768);       // [4][768] (E)

    const int len0 = lens[b0], len1 = lens[b1];
    if (tid < 256) hcs[tid] = make_float2(0.f, 0.f);

    const float bi0 = bih[j], bi1 = bih[j + 256], bi2 = bih[j + 512];
    const float bh0 = bhh[j], bh1 = bhh[j + 256], bh2 = bhh[j + 512];

    int t, tstep, nsteps;
    if (!dir) { t = 0; tstep = 1; nsteps = TH; }                      // fwd: only t<512 observable
    else { int mx = max(len0, len1); t = mx - 1; tstep = -1; nsteps = mx; } // bwd: h==0 while masked

    float x0 = 0.f, x1 = 0.f, hm0 = 0.f, hm1 = 0.f, hs0 = 0.f, hs1 = 0.f;
    int tok0 = 0, tok1 = 0;
    if (tid < 256) { tok0 = sents[b0 * Tt + t]; tok1 = sents[b1 * Tt + t]; }
    __syncthreads();

    W4 pfM; W6 pfG;
    ld4(pfM, MpQ);                             // prime phase-A block0

    auto psum = [&]() -> float2 {
        float s0 = 0.f, s1 = 0.f;
        #pragma unroll
        for (int p = 0; p < 8; ++p) { float2 v = part[p][j]; s0 += v.x; s1 += v.y; }
        return make_float2(s0, s1);
    };
    auto storeP = [&](const float* s) {
        part[ks8][l64      ] = make_float2(s[0], s[1]);
        part[ks8][l64 +  64] = make_float2(s[2], s[3]);
        part[ks8][l64 + 128] = make_float2(s[4], s[5]);
        part[ks8][l64 + 192] = make_float2(s[6], s[7]);
    };

    for (int s = 0; s < nsteps; ++s, t += tstep) {
        if (tid < 256) {                      // emb gather resolves under phase A
            x0 = emb[(size_t)tok0 * 256 + j];
            x1 = emb[(size_t)tok1 * 256 + j];
            if (s + 1 < nsteps) {
                int tn = t + tstep;
                tok0 = sents[b0 * Tt + tn];
                tok1 = sents[b1 * Tt + tn];
            }
        }
        // ---- A: x = 2*sig(hc @ Q) * x ----
        {
            float sa[8] = {0,0,0,0,0,0,0,0};
            mog_phase<false>(MpQ, (const float4*)hcs, k4m, pfM, MpR, pfG, Wg, sa);
            storeP(sa);
        }
        __syncthreads();
        if (tid < 256) {
            float2 sv = psum();
            x0 *= 2.f * sigm(sv.x);  x1 *= 2.f * sigm(sv.y);
            xs[j] = make_float2(x0, x1);
        }
        __syncthreads();
        // ---- B: hm = 2*sig(x @ R) * hc ----
        {
            float sa[8] = {0,0,0,0,0,0,0,0};
            mog_phase<false>(MpR, (const float4*)xs, k4m, pfM, MpQ, pfG, Wg, sa);
            storeP(sa);
        }
        __syncthreads();
        if (tid < 256) {
            float2 sv = psum();
            float2 hcj = hcs[j];
            hs0 = hcj.x; hs1 = hcj.y;
            hm0 = 2.f * sigm(sv.x) * hcj.x;  hm1 = 2.f * sigm(sv.y) * hcj.y;
            hms[j] = make_float2(hm0, hm1);
        }
        __syncthreads();
        // ---- C: x = 2*sig(hm @ Q) * x ----
        {
            float sa[8] = {0,0,0,0,0,0,0,0};
            mog_phase<false>(MpQ, (const float4*)hms, k4m, pfM, MpR, pfG, Wg, sa);
            storeP(sa);
        }
        __syncthreads();
        if (tid < 256) {
            float2 sv = psum();
            x0 *= 2.f * sigm(sv.x);  x1 *= 2.f * sigm(sv.y);
            xs[j] = make_float2(x0, x1);
        }
        __syncthreads();
        // ---- D: hm = 2*sig(x @ R) * hm ----  (tail prefetches GRU block0)
        {
            float sa[8] = {0,0,0,0,0,0,0,0};
            mog_phase<true>(MpR, (const float4*)xs, k4m, pfM, MpQ, pfG, Wg, sa);
            storeP(sa);
        }
        __syncthreads();
        if (tid < 256) {
            float2 sv = psum();
            hm0 *= 2.f * sigm(sv.x);  hm1 *= 2.f * sigm(sv.y);
            hms[j] = make_float2(hm0, hm1);
        }
        __syncthreads();
        // ---- E: gi = x@Wih^T, gh = hm@Whh^T  (two 6-col passes, dbuf) ----
        {
            const float4* LvE = mh ? (const float4*)hms : (const float4*)xs;
            float2 (*dst)[768] = mh ? ghP : giP;
            float g[12] = {0,0,0,0,0,0,0,0,0,0,0,0};
            gru_pass<false>(Wg, LvE, k4e, pfG, Wg + 384, pfM, MpQ, g);
            #pragma unroll
            for (int cc = 0; cc < 6; ++cc)
                dst[ks4][l2 + 64 * cc] = make_float2(g[2*cc], g[2*cc+1]);
            float g2[12] = {0,0,0,0,0,0,0,0,0,0,0,0};
            gru_pass<true>(Wg + 384, LvE, k4e, pfG, Wg, pfM, MpQ, g2);
            #pragma unroll
            for (int cc = 0; cc < 6; ++cc)
                dst[ks4][l2 + 384 + 64 * cc] = make_float2(g2[2*cc], g2[2*cc+1]);
        }
        __syncthreads();
        if (tid < 256) {
            float gix[3], giy[3], ghx[3], ghy[3];
            #pragma unroll
            for (int g = 0; g < 3; ++g) {
                float s0=0,s1=0,t0=0,t1=0;
                #pragma unroll
                for (int p = 0; p < 4; ++p) {
                    float2 vi = giP[p][j + 256*g]; s0 += vi.x; s1 += vi.y;
                    float2 vh = ghP[p][j + 256*g]; t0 += vh.x; t1 += vh.y;
                }
                gix[g]=s0; giy[g]=s1; ghx[g]=t0; ghy[g]=t1;
            }
            float r0 = sigm(gix[0]+bi0 + ghx[0]+bh0), r1 = sigm(giy[0]+bi0 + ghy[0]+bh0);
            float z0 = sigm(gix[1]+bi1 + ghx[1]+bh1), z1 = sigm(giy[1]+bi1 + ghy[1]+bh1);
            float n0 = tanhf(gix[2]+bi2 + r0*(ghx[2]+bh2));
            float n1 = tanhf(giy[2]+bi2 + r1*(ghy[2]+bh2));
            float u0 = (1.f - z0) * n0 + z0 * hm0;
            float u1 = (1.f - z1) * n1 + z1 * hm1;
            bool m0 = (t < len0), m1 = (t < len1);
            hcs[j] = make_float2(m0 ? u0 : hs0, m1 ? u1 : hs1);
            if (t < TH) {
                atomicAdd(&enc[((size_t)b0 * TH + t) * Hh + j], m0 ? u0 : 0.f);
                atomicAdd(&enc[((size_t)b1 * TH + t) * Hh + j], m1 ? u1 : 0.f);
            }
        }
        __syncthreads();
    }
}

// One WG per batch element. Reproduces gate_attention + attention + dense exactly.
__global__ __launch_bounds__(256) void epi_k(
    const float* __restrict__ enc,
    const int* __restrict__ entities, const int* __restrict__ slices,
    const float* __restrict__ slice_lens,
    const int* __restrict__ entity_masks, const int* __restrict__ slice_masks,
    const float* __restrict__ ent_W, const float* __restrict__ ent_b,
    const float* __restrict__ att_w,
    const float* __restrict__ dense_W, const float* __restrict__ dense_b,
    float* __restrict__ out)
{
    const int b = blockIdx.x;
    const int j = threadIdx.x;
    const int wave = j >> 6, lane = j & 63;

    __shared__ float ee[8][256];
    __shared__ float p[256];
    __shared__ float rela[256];
    __shared__ float sc[264];
    __shared__ float red[4];
    __shared__ float aw[256];
    __shared__ int   spos[256];

    aw[j]   = att_w[j];
    spos[j] = slices[b * 256 + j];
    #pragma unroll
    for (int e = 0; e < 8; ++e)
        ee[e][j] = enc[((size_t)b * TH + entities[b * 8 + e]) * 256 + j];
    __syncthreads();

    float entWj = ent_W[j];
    for (int e = 0; e < 8; ++e) {
        float v = ee[e][j] * entWj;
        #pragma unroll
        for (int o = 32; o > 0; o >>= 1) v += __shfl_down(v, o);
        if (lane == 0) red[wave] = v;
        __syncthreads();
        if (j == 0) sc[e] = red[0] + red[1] + red[2] + red[3] + ent_b[0];
        __syncthreads();
    }
    float mx = -INFINITY;
    float ewv[8];
    #pragma unroll
    for (int e = 0; e < 8; ++e) {
        float v = entity_masks[b * 8 + e] ? sc[e] : -INFINITY;
        ewv[e] = v; mx = fmaxf(mx, v);
    }
    float den = 0.f;
    #pragma unroll
    for (int e = 0; e < 8; ++e) {
        ewv[e] = entity_masks[b * 8 + e] ? expf(ewv[e] - mx) : 0.f;
        den += ewv[e];
    }
    float accp = 0.f;
    #pragma unroll
    for (int e = 0; e < 8; ++e) accp += (ewv[e] / den) * ee[e][j];
    p[j] = tanhf(accp);
    __syncthreads();

    for (int s0 = wave; s0 < 256; s0 += 4) {
        const float* row = enc + ((size_t)b * TH + spos[s0]) * 256;
        float v = 0.f;
        #pragma unroll
        for (int i = 0; i < 4; ++i) { int c = lane + 64 * i; v += row[c] * p[c]; }
        #pragma unroll
        for (int o = 32; o > 0; o >>= 1) v += __shfl_down(v, o);
        if (lane == 0) sc[s0] = v;
    }
    __syncthreads();

    float sl  = slice_lens[b];
    int   smk = slice_masks[b * 256 + j];
    float wv  = smk ? sc[j] : -INFINITY;
    float bm = wv;
    #pragma unroll
    for (int o = 32; o > 0; o >>= 1) bm = fmaxf(bm, __shfl_down(bm, o));
    __syncthreads();
    if (lane == 0) red[wave] = bm;
    __syncthreads();
    bm = fmaxf(fmaxf(red[0], red[1]), fmaxf(red[2], red[3]));
    float ex = smk ? expf(wv - bm) : 0.f;
    float sm2 = ex;
    #pragma unroll
    for (int o = 32; o > 0; o >>= 1) sm2 += __shfl_down(sm2, o);
    __syncthreads();
    if (lane == 0) red[wave] = sm2;
    __syncthreads();
    sm2 = red[0] + red[1] + red[2] + red[3];
    float ww = ex / sm2 * sl;
    float rl = (ww > 0.05f) ? (ww / sl) : 0.f;   // BETA = 0.05
    float rm = rl;
    #pragma unroll
    for (int o = 32; o > 0; o >>= 1) rm = fmaxf(rm, __shfl_down(rm, o));
    __syncthreads();
    if (lane == 0) red[wave] = rm;
    __syncthreads();
    rm = fmaxf(fmaxf(red[0], red[1]), fmaxf(red[2], red[3]));
    rl = rl / rm;
    rela[j] = rl;
    __syncthreads();

    for (int n = wave; n < 264; n += 4) {
        float v = 0.f;
        if (n < 8) {
            #pragma unroll
            for (int i = 0; i < 4; ++i) { int c = lane + 64 * i; v += tanhf(ee[n][c]) * aw[c]; }
        } else {
            int s0 = n - 8;
            const float* row = enc + ((size_t)b * TH + spos[s0]) * 256;
            float rl2 = rela[s0];
            #pragma unroll
            for (int i = 0; i < 4; ++i) { int c = lane + 64 * i; v += tanhf(rl2 * row[c]) * aw[c]; }
        }
        #pragma unroll
        for (int o = 32; o > 0; o >>= 1) v += __shfl_down(v, o);
        if (lane == 0) sc[n] = v;
    }
    __syncthreads();

    float a1 = sc[j];       a1 = (a1 == 0.f) ? -INFINITY : a1;
    float a2 = (j < 8) ? sc[256 + j] : -INFINITY;
    if (a2 == 0.f) a2 = -INFINITY;
    float am = fmaxf(a1, a2);
    #pragma unroll
    for (int o = 32; o > 0; o >>= 1) am = fmaxf(am, __shfl_down(am, o));
    __syncthreads();
    if (lane == 0) red[wave] = am;
    __syncthreads();
    am = fmaxf(fmaxf(red[0], red[1]), fmaxf(red[2], red[3]));
    float e1 = (a1 == -INFINITY) ? 0.f : expf(a1 - am);
    float e2 = (a2 == -INFINITY) ? 0.f : expf(a2 - am);
    float esum = e1 + e2;
    #pragma unroll
    for (int o = 32; o > 0; o >>= 1) esum += __shfl_down(esum, o);
    __syncthreads();
    if (lane == 0) red[wave] = esum;
    __syncthreads();
    esum = red[0] + red[1] + red[2] + red[3];
    __syncthreads();
    sc[j] = e1 / esum;
    if (j < 8) sc[256 + j] = e2 / esum;
    __syncthreads();

    float att = 0.f;
    #pragma unroll
    for (int n = 0; n < 8; ++n) att += sc[n] * ee[n][j];
    for (int s0 = 0; s0 < 256; ++s0) {
        float scn = sc[8 + s0];
        if (scn > 0.f)
            att += scn * rela[s0] * enc[((size_t)b * TH + spos[s0]) * 256 + j];
    }
    float ta = tanhf(att);

    for (int l = 0; l < 19; ++l) {
        float v = ta * dense_W[l * 256 + j];
        #pragma unroll
        for (int o = 32; o > 0; o >>= 1) v += __shfl_down(v, o);
        __syncthreads();
        if (lane == 0) red[wave] = v;
        __syncthreads();
        if (j == 0) out[b * 19 + l] = red[0] + red[1] + red[2] + red[3] + dense_b[l];
    }
}

extern "C" void kernel_launch(void* const* d_in, const int* in_sizes, int n_in,
                              void* d_out, int out_size, void* d_ws, size_t ws_size,
                              hipStream_t stream) {
    (void)in_sizes; (void)n_in; (void)out_size; (void)ws_size;
    const int*   sents        = (const int*)d_in[0];
    const int*   lens         = (const int*)d_in[1];
    const int*   entities     = (const int*)d_in[2];
    const int*   slices       = (const int*)d_in[3];
    const float* slice_lens   = (const float*)d_in[4];
    const int*   entity_masks = (const int*)d_in[5];
    const int*   slice_masks  = (const int*)d_in[6];
    const float* emb          = (const float*)d_in[7];
    const float* Q            = (const float*)d_in[8];
    const float* R            = (const float*)d_in[9];
    const float* Wih_f        = (const float*)d_in[10];
    const float* Whh_f        = (const float*)d_in[11];
    const float* bih_f        = (const float*)d_in[12];
    const float* bhh_f        = (const float*)d_in[13];
    const float* Wih_b        = (const float*)d_in[14];
    const float* Whh_b        = (const float*)d_in[15];
    const float* bih_b        = (const float*)d_in[16];
    const float* bhh_b        = (const float*)d_in[17];
    const float* ent_W        = (const float*)d_in[18];
    const float* ent_b        = (const float*)d_in[19];
    const float* att_w        = (const float*)d_in[20];
    const float* dense_W      = (const float*)d_in[21];
    const float* dense_b      = (const float*)d_in[22];

    // ws layout (floats): enc [64][512][256] | Qp 32768 f4 | Rp 32768 f4 | Wip 98304 f4 | Whp 98304 f4
    float*  enc = (float*)d_ws;
    float4* Qp  = (float4*)(enc + (size_t)Bsz * TH * Hh);
    float4* Rp  = Qp + 32768;
    float4* Wip = Rp + 32768;
    float4* Whp = Wip + 98304;

    hipMemsetAsync(enc, 0, (size_t)Bsz * TH * Hh * sizeof(float), stream);
    pack_k<<<384, 256, 0, stream>>>(Q, R, Wih_f, Whh_f, Wih_b, Whh_b, Qp, Rp, Wip, Whp);
    scan_k<<<64, 512, 0, stream>>>(sents, lens, emb,
                                   bih_f, bhh_f, bih_b, bhh_b,
                                   Qp, Rp, Wip, Whp, enc);
    epi_k<<<64, 256, 0, stream>>>(enc, entities, slices, slice_lens,
                                  entity_masks, slice_masks, ent_W, ent_b,
                                  att_w, dense_W, dense_b, (float*)d_out);
}

// Round 6
// 24348.065 us; speedup vs baseline: 10.5243x; 10.5243x over previous
//
#include <hip/hip_runtime.h>
#include <math.h>

#define Bsz 64
#define Tt  1024
#define TH  512      // entities/slices < T/2, lens >= T/2 -> enc only needed for t < 512
#define SLOT 1024    // floats per 4KB DMA slot

__device__ __forceinline__ float sigm(float x) { return 1.0f / (1.0f + expf(-x)); }

#define GLOAD16(g,l) __builtin_amdgcn_global_load_lds( \
    (const __attribute__((address_space(1))) void*)(g), \
    (__attribute__((address_space(3))) void*)(l), 16, 0, 0)
#define WAITV8 asm volatile("s_waitcnt vmcnt(8)":::"memory")
#define WAITV4 asm volatile("s_waitcnt vmcnt(4)":::"memory")
#define WAITV0 asm volatile("s_waitcnt vmcnt(0)":::"memory")
#define WAITLG asm volatile("s_waitcnt lgkmcnt(0)":::"memory")

// Repack weights into per-(dir,wave) consumption-ordered f4 streams.
// Mog (Q,R): wave w owns k4 in [8w,8w+8); unit i = one k4-row of 256 cols.
//   Qs/Rs[((d*8+w)*8 + i)*256 + col] = {W[k0..k0+3][col]}, k0 = 32w+4i.
// GRU: wave w: mh=w&1 (0:Wih,1:Whh), ks4=w>>1 owns k4 in [16ks4,+16).
//   unit u: row=u/3 (local k4), colblock=(u%3)*256.
//   Gs[((d*8+w)*48 + u)*256 + t] = {W[outcol][4k4g..+3]}, outcol=cb+t.
__global__ void pack_k(const float* __restrict__ Q, const float* __restrict__ R,
                       const float* __restrict__ Wih_f, const float* __restrict__ Whh_f,
                       const float* __restrict__ Wih_b, const float* __restrict__ Whh_b,
                       float4* __restrict__ Qs, float4* __restrict__ Rs,
                       float4* __restrict__ Gs)
{
    int idx = blockIdx.x * 256 + threadIdx.x;
    if (idx < 65536) {
        int col = idx & 255;
        int r = idx >> 8;                  // ((d*8+w)*8+i), 0..255
        int i = r & 7, wv = (r >> 3) & 7, d = r >> 6;
        int k0 = 32 * wv + 4 * i;
        const float* Sq = Q + d * 65536;
        Qs[idx] = make_float4(Sq[(k0+0)*256+col], Sq[(k0+1)*256+col],
                              Sq[(k0+2)*256+col], Sq[(k0+3)*256+col]);
        const float* Sr = R + d * 65536;
        Rs[idx] = make_float4(Sr[(k0+0)*256+col], Sr[(k0+1)*256+col],
                              Sr[(k0+2)*256+col], Sr[(k0+3)*256+col]);
    }
    if (idx < 196608) {
        int tc = idx & 255;
        int r = idx >> 8;                  // (d*8+w)*48 + u
        int u = r % 48; int dw = r / 48; int wv = dw & 7, d = dw >> 3;
        int mh = wv & 1, ks4 = wv >> 1;
        int row = u / 3, cbk = (u % 3) * 256;
        int outcol = cbk + tc;
        int k4g = 16 * ks4 + row;
        const float* W = mh ? (d ? Whh_b : Whh_f) : (d ? Wih_b : Wih_f);
        Gs[idx] = *(const float4*)(W + outcol * 256 + 4 * k4g);
    }
}

// One WG of 512 threads per (direction, batch-pair), dir grouped per XCD.
// Weights stream global->LDS via global_load_lds, per-wave 3-slot ring,
// counted vmcnt (no extra barriers). Finalize spread over all 512 threads.
__global__ __launch_bounds__(512) void scan_k(
    const int* __restrict__ sents, const int* __restrict__ lens,
    const float* __restrict__ emb,
    const float* __restrict__ bih_f, const float* __restrict__ bhh_f,
    const float* __restrict__ bih_b, const float* __restrict__ bhh_b,
    const float4* __restrict__ Qs, const float4* __restrict__ Rs,
    const float4* __restrict__ Gs, float* __restrict__ enc)
{
    extern __shared__ float sm[];
    float* xs_f  = sm;                     // [256][2] (col-major pairs)
    float* hcs_f = sm + 512;
    float* hms_f = sm + 1024;
    float* PART  = sm + 1536;              // 12288 floats (mog part overlaid in giP)
    float* DMA   = sm + 1536 + 12288;      // [8 waves][3 slots][1024]

    const int w = blockIdx.x;                  // 0..63
    const int dir  = ((w & 7) >= 4) ? 1 : 0;   // dir constant per XCD residue class
    const int pair = (w >> 3) * 4 + (w & 3);   // 0..31, unique per dir
    const int b0 = pair * 2, b1 = b0 + 1;
    const int tid = threadIdx.x;
    const int wv = tid >> 6, ln = tid & 63;
    const int cj = tid & 255, cb = tid >> 8;   // finalize (col, batch)
    const int ks4 = wv >> 1;                   // GRU k-slice (mat = wv&1)

    float* wbuf = DMA + wv * (3 * SLOT);
    const float4* Qw = Qs + ((dir * 8 + wv) << 11);
    const float4* Rw = Rs + ((dir * 8 + wv) << 11);
    const float4* Gw = Gs + (dir * 8 + wv) * 12288;
    const float* bih = dir ? bih_b : bih_f;
    const float* bhh = dir ? bhh_b : bhh_f;

    const int len0 = lens[b0], len1 = lens[b1];
    const int myb = cb ? b1 : b0;
    const int mylen = cb ? len1 : len0;

    const float bi_r = bih[cj], bi_z = bih[cj + 256], bi_n = bih[cj + 512];
    const float bh_r = bhh[cj], bh_z = bhh[cj + 256], bh_n = bhh[cj + 512];

    hcs_f[2 * cj + cb] = 0.f;

    int t, tstep, nsteps;
    if (!dir) { t = 0; tstep = 1; nsteps = TH; }                      // fwd: t<512 observable
    else { int mx = max(len0, len1); t = mx - 1; tstep = -1; nsteps = mx; } // bwd: h==0 while masked

    int tok = sents[myb * Tt + t];
    float xv = 0.f, hm = 0.f, hs = 0.f;
    __syncthreads();

    #define ISSUEU(base, u, slot) do { \
        const float4* gg = (base) + ((u) << 8) + ln; \
        float* llp = wbuf + (slot) * SLOT; \
        GLOAD16(gg,       llp      ); \
        GLOAD16(gg +  64, llp + 256); \
        GLOAD16(gg + 128, llp + 512); \
        GLOAD16(gg + 192, llp + 768); \
    } while (0)

    auto FMA2 = [](const float4 wq, const float4 v01, const float4 v23,
                   float& s0, float& s1) {
        s0 = fmaf(wq.x, v01.x, fmaf(wq.y, v01.z, fmaf(wq.z, v23.x, fmaf(wq.w, v23.z, s0))));
        s1 = fmaf(wq.x, v01.y, fmaf(wq.y, v01.w, fmaf(wq.z, v23.y, fmaf(wq.w, v23.w, s1))));
    };

    // Mogrify matvec slice: 8 units, 3-deep DMA ring, writes part[wv].
    auto mog = [&](const float4* base, const float* acts) {
        const float4* Lv = (const float4*)acts;
        float a0[4] = {0,0,0,0}, a1[4] = {0,0,0,0};
        ISSUEU(base, 0, 0); ISSUEU(base, 1, 1); ISSUEU(base, 2, 2);
        #pragma unroll
        for (int u = 0; u < 8; ++u) {
            if (u <= 5) WAITV8; else if (u == 6) WAITV4; else WAITV0;
            const float* bp = wbuf + (u % 3) * SLOT;
            float4 w0 = *(const float4*)(bp + 4 * ln);
            float4 w1 = *(const float4*)(bp + 4 * (64 + ln));
            float4 w2 = *(const float4*)(bp + 4 * (128 + ln));
            float4 w3 = *(const float4*)(bp + 4 * (192 + ln));
            float4 v01 = Lv[16 * wv + 2 * u];
            float4 v23 = Lv[16 * wv + 2 * u + 1];
            WAITLG;                                   // reads done before slot reuse
            if (u < 5) ISSUEU(base, u + 3, u % 3);
            FMA2(w0, v01, v23, a0[0], a1[0]);
            FMA2(w1, v01, v23, a0[1], a1[1]);
            FMA2(w2, v01, v23, a0[2], a1[2]);
            FMA2(w3, v01, v23, a0[3], a1[3]);
        }
        #pragma unroll
        for (int c = 0; c < 4; ++c) {
            int col = (c << 6) + ln;
            PART[(wv * 256 + col) * 2    ] = a0[c];
            PART[(wv * 256 + col) * 2 + 1] = a1[c];
        }
    };

    // GRU matmul slice: 48 units (16 rows x 3 col-blocks), same DMA ring.
    auto gru = [&]() {
        const float* acts = (wv & 1) ? hms_f : xs_f;
        const float4* Lv = (const float4*)acts;
        float g0[12], g1[12];
        #pragma unroll
        for (int c = 0; c < 12; ++c) { g0[c] = 0.f; g1[c] = 0.f; }
        ISSUEU(Gw, 0, 0); ISSUEU(Gw, 1, 1); ISSUEU(Gw, 2, 2);
        for (int ug = 0; ug < 15; ++ug) {
            const float4 v01 = Lv[2 * (16 * ks4 + ug)];
            const float4 v23 = Lv[2 * (16 * ks4 + ug) + 1];
            const int un = 3 * (ug + 1);
            #pragma unroll
            for (int q = 0; q < 3; ++q) {
                WAITV8;
                const float* bp = wbuf + q * SLOT;
                float4 w0 = *(const float4*)(bp + 4 * ln);
                float4 w1 = *(const float4*)(bp + 4 * (64 + ln));
                float4 w2 = *(const float4*)(bp + 4 * (128 + ln));
                float4 w3 = *(const float4*)(bp + 4 * (192 + ln));
                WAITLG;
                ISSUEU(Gw, un + q, q);
                FMA2(w0, v01, v23, g0[q*4+0], g1[q*4+0]);
                FMA2(w1, v01, v23, g0[q*4+1], g1[q*4+1]);
                FMA2(w2, v01, v23, g0[q*4+2], g1[q*4+2]);
                FMA2(w3, v01, v23, g0[q*4+3], g1[q*4+3]);
            }
        }
        {   // tail row 15, no further issues
            const float4 v01 = Lv[2 * (16 * ks4 + 15)];
            const float4 v23 = Lv[2 * (16 * ks4 + 15) + 1];
            #pragma unroll
            for (int q = 0; q < 3; ++q) {
                if (q == 0) WAITV8; else if (q == 1) WAITV4; else WAITV0;
                const float* bp = wbuf + q * SLOT;
                float4 w0 = *(const float4*)(bp + 4 * ln);
                float4 w1 = *(const float4*)(bp + 4 * (64 + ln));
                float4 w2 = *(const float4*)(bp + 4 * (128 + ln));
                float4 w3 = *(const float4*)(bp + 4 * (192 + ln));
                FMA2(w0, v01, v23, g0[q*4+0], g1[q*4+0]);
                FMA2(w1, v01, v23, g0[q*4+1], g1[q*4+1]);
                FMA2(w2, v01, v23, g0[q*4+2], g1[q*4+2]);
                FMA2(w3, v01, v23, g0[q*4+3], g1[q*4+3]);
            }
        }
        const int dbase = (wv & 1) ? 6144 : 0;       // giP | ghP float base
        #pragma unroll
        for (int q = 0; q < 3; ++q)
            #pragma unroll
            for (int c = 0; c < 4; ++c) {
                int col = q * 256 + (c << 6) + ln;
                PART[dbase + (ks4 * 768 + col) * 2    ] = g0[q*4+c];
                PART[dbase + (ks4 * 768 + col) * 2 + 1] = g1[q*4+c];
            }
    };

    for (int s = 0; s < nsteps; ++s, t += tstep) {
        xv = emb[(size_t)tok * 256 + cj];            // issues first, retires first
        int tokn = 0;
        if (s + 1 < nsteps) tokn = sents[myb * Tt + (t + tstep)];

        // A: x = 2*sig(hc @ Q) * x
        mog(Qw, hcs_f);
        __syncthreads();
        {
            float sv = 0.f;
            #pragma unroll
            for (int p = 0; p < 8; ++p) sv += PART[(p * 256 + cj) * 2 + cb];
            xv *= 2.f * sigm(sv);
            xs_f[2 * cj + cb] = xv;
        }
        __syncthreads();
        // B: hm = 2*sig(x @ R) * hc
        mog(Rw, xs_f);
        __syncthreads();
        {
            float sv = 0.f;
            #pragma unroll
            for (int p = 0; p < 8; ++p) sv += PART[(p * 256 + cj) * 2 + cb];
            hs = hcs_f[2 * cj + cb];
            hm = 2.f * sigm(sv) * hs;
            hms_f[2 * cj + cb] = hm;
        }
        __syncthreads();
        // C: x = 2*sig(hm @ Q) * x
        mog(Qw, hms_f);
        __syncthreads();
        {
            float sv = 0.f;
            #pragma unroll
            for (int p = 0; p < 8; ++p) sv += PART[(p * 256 + cj) * 2 + cb];
            xv *= 2.f * sigm(sv);
            xs_f[2 * cj + cb] = xv;
        }
        __syncthreads();
        // D: hm = 2*sig(x @ R) * hm
        mog(Rw, xs_f);
        __syncthreads();
        {
            float sv = 0.f;
            #pragma unroll
            for (int p = 0; p < 8; ++p) sv += PART[(p * 256 + cj) * 2 + cb];
            hm *= 2.f * sigm(sv);
            hms_f[2 * cj + cb] = hm;
        }
        __syncthreads();
        // E: GRU
        gru();
        __syncthreads();
        {
            float gir = 0, giz = 0, gin = 0, ghr = 0, ghz = 0, ghn = 0;
            #pragma unroll
            for (int p = 0; p < 4; ++p) {
                gir += PART[(p * 768 + cj      ) * 2 + cb];
                giz += PART[(p * 768 + cj + 256) * 2 + cb];
                gin += PART[(p * 768 + cj + 512) * 2 + cb];
                ghr += PART[6144 + (p * 768 + cj      ) * 2 + cb];
                ghz += PART[6144 + (p * 768 + cj + 256) * 2 + cb];
                ghn += PART[6144 + (p * 768 + cj + 512) * 2 + cb];
            }
            float r = sigm(gir + bi_r + ghr + bh_r);
            float z = sigm(giz + bi_z + ghz + bh_z);
            float n = tanhf(gin + bi_n + r * (ghn + bh_n));
            float u_ = (1.f - z) * n + z * hm;
            bool m = (t < mylen);
            hcs_f[2 * cj + cb] = m ? u_ : hs;
            if (t < TH)
                atomicAdd(&enc[((size_t)myb * TH + t) * 256 + cj], m ? u_ : 0.f);
        }
        tok = tokn;
        __syncthreads();
    }
    #undef ISSUEU
}

// One WG per batch element. Reproduces gate_attention + attention + dense exactly.
__global__ __launch_bounds__(256) void epi_k(
    const float* __restrict__ enc,
    const int* __restrict__ entities, const int* __restrict__ slices,
    const float* __restrict__ slice_lens,
    const int* __restrict__ entity_masks, const int* __restrict__ slice_masks,
    const float* __restrict__ ent_W, const float* __restrict__ ent_b,
    const float* __restrict__ att_w,
    const float* __restrict__ dense_W, const float* __restrict__ dense_b,
    float* __restrict__ out)
{
    const int b = blockIdx.x;
    const int j = threadIdx.x;
    const int wave = j >> 6, lane = j & 63;

    __shared__ float ee[8][256];
    __shared__ float p[256];
    __shared__ float rela[256];
    __shared__ float sc[264];
    __shared__ float red[4];
    __shared__ float aw[256];
    __shared__ int   spos[256];

    aw[j]   = att_w[j];
    spos[j] = slices[b * 256 + j];
    #pragma unroll
    for (int e = 0; e < 8; ++e)
        ee[e][j] = enc[((size_t)b * TH + entities[b * 8 + e]) * 256 + j];
    __syncthreads();

    float entWj = ent_W[j];
    for (int e = 0; e < 8; ++e) {
        float v = ee[e][j] * entWj;
        #pragma unroll
        for (int o = 32; o > 0; o >>= 1) v += __shfl_down(v, o);
        if (lane == 0) red[wave] = v;
        __syncthreads();
        if (j == 0) sc[e] = red[0] + red[1] + red[2] + red[3] + ent_b[0];
        __syncthreads();
    }
    float mx = -INFINITY;
    float ewv[8];
    #pragma unroll
    for (int e = 0; e < 8; ++e) {
        float v = entity_masks[b * 8 + e] ? sc[e] : -INFINITY;
        ewv[e] = v; mx = fmaxf(mx, v);
    }
    float den = 0.f;
    #pragma unroll
    for (int e = 0; e < 8; ++e) {
        ewv[e] = entity_masks[b * 8 + e] ? expf(ewv[e] - mx) : 0.f;
        den += ewv[e];
    }
    float accp = 0.f;
    #pragma unroll
    for (int e = 0; e < 8; ++e) accp += (ewv[e] / den) * ee[e][j];
    p[j] = tanhf(accp);
    __syncthreads();

    for (int s0 = wave; s0 < 256; s0 += 4) {
        const float* row = enc + ((size_t)b * TH + spos[s0]) * 256;
        float v = 0.f;
        #pragma unroll
        for (int i = 0; i < 4; ++i) { int c = lane + 64 * i; v += row[c] * p[c]; }
        #pragma unroll
        for (int o = 32; o > 0; o >>= 1) v += __shfl_down(v, o);
        if (lane == 0) sc[s0] = v;
    }
    __syncthreads();

    float sl  = slice_lens[b];
    int   smk = slice_masks[b * 256 + j];
    float wv  = smk ? sc[j] : -INFINITY;
    float bm = wv;
    #pragma unroll
    for (int o = 32; o > 0; o >>= 1) bm = fmaxf(bm, __shfl_down(bm, o));
    __syncthreads();
    if (lane == 0) red[wave] = bm;
    __syncthreads();
    bm = fmaxf(fmaxf(red[0], red[1]), fmaxf(red[2], red[3]));
    float ex = smk ? expf(wv - bm) : 0.f;
    float sm2 = ex;
    #pragma unroll
    for (int o = 32; o > 0; o >>= 1) sm2 += __shfl_down(sm2, o);
    __syncthreads();
    if (lane == 0) red[wave] = sm2;
    __syncthreads();
    sm2 = red[0] + red[1] + red[2] + red[3];
    float ww = ex / sm2 * sl;
    float rl = (ww > 0.05f) ? (ww / sl) : 0.f;   // BETA = 0.05
    float rm = rl;
    #pragma unroll
    for (int o = 32; o > 0; o >>= 1) rm = fmaxf(rm, __shfl_down(rm, o));
    __syncthreads();
    if (lane == 0) red[wave] = rm;
    __syncthreads();
    rm = fmaxf(fmaxf(red[0], red[1]), fmaxf(red[2], red[3]));
    rl = rl / rm;
    rela[j] = rl;
    __syncthreads();

    for (int n = wave; n < 264; n += 4) {
        float v = 0.f;
        if (n < 8) {
            #pragma unroll
            for (int i = 0; i < 4; ++i) { int c = lane + 64 * i; v += tanhf(ee[n][c]) * aw[c]; }
        } else {
            int s0 = n - 8;
            const float* row = enc + ((size_t)b * TH + spos[s0]) * 256;
            float rl2 = rela[s0];
            #pragma unroll
            for (int i = 0; i < 4; ++i) { int c = lane + 64 * i; v += tanhf(rl2 * row[c]) * aw[c]; }
        }
        #pragma unroll
        for (int o = 32; o > 0; o >>= 1) v += __shfl_down(v, o);
        if (lane == 0) sc[n] = v;
    }
    __syncthreads();

    float a1 = sc[j];       a1 = (a1 == 0.f) ? -INFINITY : a1;
    float a2 = (j < 8) ? sc[256 + j] : -INFINITY;
    if (a2 == 0.f) a2 = -INFINITY;
    float am = fmaxf(a1, a2);
    #pragma unroll
    for (int o = 32; o > 0; o >>= 1) am = fmaxf(am, __shfl_down(am, o));
    __syncthreads();
    if (lane == 0) red[wave] = am;
    __syncthreads();
    am = fmaxf(fmaxf(red[0], red[1]), fmaxf(red[2], red[3]));
    float e1 = (a1 == -INFINITY) ? 0.f : expf(a1 - am);
    float e2 = (a2 == -INFINITY) ? 0.f : expf(a2 - am);
    float esum = e1 + e2;
    #pragma unroll
    for (int o = 32; o > 0; o >>= 1) esum += __shfl_down(esum, o);
    __syncthreads();
    if (lane == 0) red[wave] = esum;
    __syncthreads();
    esum = red[0] + red[1] + red[2] + red[3];
    __syncthreads();
    sc[j] = e1 / esum;
    if (j < 8) sc[256 + j] = e2 / esum;
    __syncthreads();

    float att = 0.f;
    #pragma unroll
    for (int n = 0; n < 8; ++n) att += sc[n] * ee[n][j];
    for (int s0 = 0; s0 < 256; ++s0) {
        float scn = sc[8 + s0];
        if (scn > 0.f)
            att += scn * rela[s0] * enc[((size_t)b * TH + spos[s0]) * 256 + j];
    }
    float ta = tanhf(att);

    for (int l = 0; l < 19; ++l) {
        float v = ta * dense_W[l * 256 + j];
        #pragma unroll
        for (int o = 32; o > 0; o >>= 1) v += __shfl_down(v, o);
        __syncthreads();
        if (lane == 0) red[wave] = v;
        __syncthreads();
        if (j == 0) out[b * 19 + l] = red[0] + red[1] + red[2] + red[3] + dense_b[l];
    }
}

extern "C" void kernel_launch(void* const* d_in, const int* in_sizes, int n_in,
                              void* d_out, int out_size, void* d_ws, size_t ws_size,
                              hipStream_t stream) {
    (void)in_sizes; (void)n_in; (void)out_size; (void)ws_size;
    const int*   sents        = (const int*)d_in[0];
    const int*   lens         = (const int*)d_in[1];
    const int*   entities     = (const int*)d_in[2];
    const int*   slices       = (const int*)d_in[3];
    const float* slice_lens   = (const float*)d_in[4];
    const int*   entity_masks = (const int*)d_in[5];
    const int*   slice_masks  = (const int*)d_in[6];
    const float* emb          = (const float*)d_in[7];
    const float* Q            = (const float*)d_in[8];
    const float* R            = (const float*)d_in[9];
    const float* Wih_f        = (const float*)d_in[10];
    const float* Whh_f        = (const float*)d_in[11];
    const float* bih_f        = (const float*)d_in[12];
    const float* bhh_f        = (const float*)d_in[13];
    const float* Wih_b        = (const float*)d_in[14];
    const float* Whh_b        = (const float*)d_in[15];
    const float* bih_b        = (const float*)d_in[16];
    const float* bhh_b        = (const float*)d_in[17];
    const float* ent_W        = (const float*)d_in[18];
    const float* ent_b        = (const float*)d_in[19];
    const float* att_w        = (const float*)d_in[20];
    const float* dense_W      = (const float*)d_in[21];
    const float* dense_b      = (const float*)d_in[22];

    // ws: enc [64][512][256] f32 | Qs 65536 f4 | Rs 65536 f4 | Gs 196608 f4
    float*  enc = (float*)d_ws;
    float4* Qs  = (float4*)(enc + (size_t)Bsz * TH * 256);
    float4* Rs  = Qs + 65536;
    float4* Gs  = Rs + 65536;

    const int smem_bytes = (1536 + 12288 + 8 * 3 * SLOT) * 4;   // 153600 B
    hipFuncSetAttribute(reinterpret_cast<const void*>(scan_k),
                        hipFuncAttributeMaxDynamicSharedMemorySize, smem_bytes);

    hipMemsetAsync(enc, 0, (size_t)Bsz * TH * 256 * sizeof(float), stream);
    pack_k<<<768, 256, 0, stream>>>(Q, R, Wih_f, Whh_f, Wih_b, Whh_b, Qs, Rs, Gs);
    scan_k<<<64, 512, smem_bytes, stream>>>(sents, lens, emb,
                                            bih_f, bhh_f, bih_b, bhh_b,
                                            Qs, Rs, Gs, enc);
    epi_k<<<64, 256, 0, stream>>>(enc, entities, slices, slice_lens,
                                  entity_masks, slice_masks, ent_W, ent_b,
                                  att_w, dense_W, dense_b, (float*)d_out);
}